// Round 1
// baseline (476.792 us; speedup 1.0000x reference)
//
#include <hip/hip_runtime.h>
#include <hip/hip_bf16.h>
#include <stdint.h>

#define D_IN 768
#define D_SAE 24576
#define BATCH 2048
#define TOPK 64

typedef _Float16 f16x8 __attribute__((ext_vector_type(8)));
typedef _Float16 f16x4 __attribute__((ext_vector_type(4)));
typedef float floatx4 __attribute__((ext_vector_type(4)));

#define AS1 __attribute__((address_space(1)))
#define AS3 __attribute__((address_space(3)))

// async global->LDS, 16B per lane, wave-uniform LDS base (HW adds lane*16)
__device__ __forceinline__ void load_lds16(const void* g, void* l) {
    __builtin_amdgcn_global_load_lds((AS1 void*)(g), (AS3 void*)(l), 16, 0, 0);
}

__device__ __forceinline__ unsigned f2key(float f) {
    unsigned u = __float_as_uint(f);
    unsigned mask = (unsigned)(((int)u) >> 31) | 0x80000000u;
    return u ^ mask;  // monotone: larger float -> larger key
}

// ---------------- prep: xc = x - b_dec (f16), zero the loss accumulator ----
__global__ __launch_bounds__(256) void prep_x_kernel(const float* __restrict__ x,
                                                     const float* __restrict__ b_dec,
                                                     _Float16* __restrict__ xch,
                                                     float* __restrict__ out) {
    if (blockIdx.x == 0 && threadIdx.x == 0) out[0] = 0.0f;
    int i = (blockIdx.x * 256 + threadIdx.x) * 4;
    if (i >= BATCH * D_IN) return;
    int c = i % D_IN;
    float4 xv = *(const float4*)(x + i);
    float4 bv = *(const float4*)(b_dec + c);
    f16x4 h;
    h[0] = (_Float16)(xv.x - bv.x);
    h[1] = (_Float16)(xv.y - bv.y);
    h[2] = (_Float16)(xv.z - bv.z);
    h[3] = (_Float16)(xv.w - bv.w);
    *(f16x4*)(xch + i) = h;
}

// ---------------- transpose W_enc [768, 24576] f32 -> WT [24576, 768] f16 --
__global__ __launch_bounds__(256) void transpose_kernel(const float* __restrict__ W,
                                                        _Float16* __restrict__ WT) {
    __shared__ _Float16 tile[32][33];
    int n0 = blockIdx.x * 32;   // over D_SAE
    int k0 = blockIdx.y * 32;   // over D_IN
    int tx = threadIdx.x & 31, ty = threadIdx.x >> 5;
#pragma unroll
    for (int r = 0; r < 4; ++r) {
        int k = k0 + ty + r * 8;
        tile[ty + r * 8][tx] = (_Float16)W[(size_t)k * D_SAE + n0 + tx];
    }
    __syncthreads();
#pragma unroll
    for (int r = 0; r < 4; ++r) {
        int n = n0 + ty + r * 8;
        WT[(size_t)n * D_IN + k0 + tx] = tile[tx][ty + r * 8];
    }
}

// ---------------- GEMM: pre[2048,24576] = xch @ WT^T + b_enc ---------------
// A = xch [BATCH, 768] f16 row-major; B^T = WT [D_SAE, 768] f16 row-major.
// 128x128 tile, BK=32, 4 waves (2x2 of 64x64), 16x16x32 f16 MFMA.
__global__ __launch_bounds__(256) void gemm_kernel(const _Float16* __restrict__ A,
                                                   const _Float16* __restrict__ BT,
                                                   const float* __restrict__ b_enc,
                                                   float* __restrict__ pre) {
    __shared__ _Float16 As[128 * 32];
    __shared__ _Float16 Bs[128 * 32];
    const int tid = threadIdx.x;
    const int lane = tid & 63;
    const int wave = tid >> 6;
    const int m0 = blockIdx.y * 128;
    const int n0 = blockIdx.x * 128;
    const int wm = wave >> 1, wn = wave & 1;
    const int colv = lane & 15, quad = lane >> 4;

    floatx4 acc[4][4];
#pragma unroll
    for (int mi = 0; mi < 4; ++mi)
#pragma unroll
        for (int ni = 0; ni < 4; ++ni)
#pragma unroll
            for (int r = 0; r < 4; ++r) acc[mi][ni][r] = 0.0f;

    for (int kt = 0; kt < 24; ++kt) {
        const int k0 = kt * 32;
        // stage A tile [128 rows x 32 k] and B tile [128 n x 32 k], both
        // row-major stride-32 in LDS. granule = 16B = 8 f16; 512 granules each.
#pragma unroll
        for (int i = 0; i < 2; ++i) {
            int gw = i * 256 + wave * 64;   // wave-uniform base granule
            int g = gw + lane;              // this lane's granule
            int r = g >> 2, kq = g & 3;
            load_lds16(A + (size_t)(m0 + r) * D_IN + k0 + kq * 8, &As[gw * 8]);
            load_lds16(BT + (size_t)(n0 + r) * D_IN + k0 + kq * 8, &Bs[gw * 8]);
        }
        __syncthreads();
        f16x8 af[4], bf[4];
#pragma unroll
        for (int mi = 0; mi < 4; ++mi)
            af[mi] = *(const f16x8*)&As[(wm * 64 + mi * 16 + colv) * 32 + quad * 8];
#pragma unroll
        for (int ni = 0; ni < 4; ++ni)
            bf[ni] = *(const f16x8*)&Bs[(wn * 64 + ni * 16 + colv) * 32 + quad * 8];
#pragma unroll
        for (int mi = 0; mi < 4; ++mi)
#pragma unroll
            for (int ni = 0; ni < 4; ++ni)
                acc[mi][ni] = __builtin_amdgcn_mfma_f32_16x16x32_f16(af[mi], bf[ni], acc[mi][ni], 0, 0, 0);
        __syncthreads();
    }
    // epilogue: C/D layout col=lane&15, row=quad*4+reg (verified m89/m91)
    float be[4];
#pragma unroll
    for (int ni = 0; ni < 4; ++ni) be[ni] = b_enc[n0 + wn * 64 + ni * 16 + colv];
#pragma unroll
    for (int mi = 0; mi < 4; ++mi) {
#pragma unroll
        for (int ni = 0; ni < 4; ++ni) {
            size_t base = (size_t)(m0 + wm * 64 + mi * 16 + quad * 4) * D_SAE
                        + (size_t)(n0 + wn * 64 + ni * 16 + colv);
#pragma unroll
            for (int r = 0; r < 4; ++r)
                pre[base + (size_t)r * D_SAE] = acc[mi][ni][r] + be[ni];
        }
    }
}

// ---------------- fused exact top-64 (radix select) + sparse decode + loss -
__global__ __launch_bounds__(1024) void topk_loss_kernel(const float* __restrict__ pre,
                                                         const float* __restrict__ x,
                                                         const float* __restrict__ W_dec,
                                                         const float* __restrict__ b_dec,
                                                         float* __restrict__ out) {
    const int row = blockIdx.x;
    const int tid = threadIdx.x;
    const float* prow = pre + (size_t)row * D_SAE;

    float v[24];
#pragma unroll
    for (int j = 0; j < 24; ++j) v[j] = prow[j * 1024 + tid];

    __shared__ int hist[256];
    __shared__ int scan[256];
    __shared__ int sh_bin, sh_K;

    unsigned prefix = 0, pmask = 0;
    int K = TOPK;

    for (int p = 3; p >= 0; --p) {
        if (tid < 256) hist[tid] = 0;
        __syncthreads();
#pragma unroll
        for (int j = 0; j < 24; ++j) {
            unsigned key = f2key(v[j]);
            if ((key & pmask) == prefix)
                atomicAdd(&hist[(key >> (8 * p)) & 255], 1);
        }
        __syncthreads();
        if (tid < 256) scan[tid] = hist[tid];
        __syncthreads();
        // suffix sum: scan[t] = sum_{b>=t} hist[b]
        for (int off = 1; off < 256; off <<= 1) {
            int add = 0;
            if (tid < 256 && tid + off < 256) add = scan[tid + off];
            __syncthreads();
            if (tid < 256) scan[tid] += add;
            __syncthreads();
        }
        if (tid < 256) {
            int G = (tid < 255) ? scan[tid + 1] : 0;  // strictly-greater count
            if (G < K && scan[tid] >= K) { sh_bin = tid; sh_K = K - G; }
        }
        __syncthreads();
        prefix |= ((unsigned)sh_bin) << (8 * p);
        pmask |= 0xFFu << (8 * p);
        K = sh_K;
        __syncthreads();
    }
    // prefix == key of the 64th-largest value; K == #ties-at-threshold to take

    __shared__ int n_eq, nsel;
    __shared__ int sel_idx[TOPK];
    __shared__ float sel_val[TOPK];
    if (tid == 0) { n_eq = 0; nsel = 0; }
    if (tid < TOPK) { sel_idx[tid] = 0; sel_val[tid] = 0.0f; }
    __syncthreads();

    const unsigned T = prefix;
#pragma unroll
    for (int j = 0; j < 24; ++j) {
        unsigned key = f2key(v[j]);
        bool take = key > T;
        if (!take && key == T) take = (atomicAdd(&n_eq, 1) < K);
        if (take && v[j] > 0.0f) {  // relu: non-positive selected vals contribute 0
            int s = atomicAdd(&nsel, 1);
            sel_idx[s] = j * 1024 + tid;
            sel_val[s] = v[j];
        }
    }
    __syncthreads();

    float local = 0.0f;
    if (tid < D_IN) {
        float r0 = b_dec[tid], r1 = 0.0f, r2 = 0.0f, r3 = 0.0f;
#pragma unroll 4
        for (int s = 0; s < TOPK; s += 4) {
            r0 += sel_val[s + 0] * W_dec[(size_t)sel_idx[s + 0] * D_IN + tid];
            r1 += sel_val[s + 1] * W_dec[(size_t)sel_idx[s + 1] * D_IN + tid];
            r2 += sel_val[s + 2] * W_dec[(size_t)sel_idx[s + 2] * D_IN + tid];
            r3 += sel_val[s + 3] * W_dec[(size_t)sel_idx[s + 3] * D_IN + tid];
        }
        float r = (r0 + r1) + (r2 + r3);
        float d = r - x[(size_t)row * D_IN + tid];
        local = d * d;
    }
    // block reduce -> one atomic per row
    __shared__ float wsum[16];
    int lane = tid & 63, w = tid >> 6;
#pragma unroll
    for (int off = 32; off > 0; off >>= 1) local += __shfl_down(local, off, 64);
    if (lane == 0) wsum[w] = local;
    __syncthreads();
    if (w == 0) {
        float s = (lane < 16) ? wsum[lane] : 0.0f;
#pragma unroll
        for (int off = 8; off > 0; off >>= 1) s += __shfl_down(s, off, 64);
        if (lane == 0) atomicAdd(out, s);
    }
}

extern "C" void kernel_launch(void* const* d_in, const int* in_sizes, int n_in,
                              void* d_out, int out_size, void* d_ws, size_t ws_size,
                              hipStream_t stream) {
    const float* x     = (const float*)d_in[0];
    const float* W_enc = (const float*)d_in[1];
    const float* W_dec = (const float*)d_in[2];
    const float* b_enc = (const float*)d_in[3];
    const float* b_dec = (const float*)d_in[4];
    float* out = (float*)d_out;

    char* ws = (char*)d_ws;
    _Float16* xch = (_Float16*)ws;                     // 2048*768*2   = 3,145,728 B
    _Float16* WT  = (_Float16*)(ws + 3145728);         // 24576*768*2  = 37,748,736 B
    float* pre    = (float*)(ws + 3145728 + 37748736); // 2048*24576*4 = 201,326,592 B
    // total ws use: ~242 MB

    prep_x_kernel<<<1536, 256, 0, stream>>>(x, b_dec, xch, out);
    transpose_kernel<<<dim3(D_SAE / 32, D_IN / 32), 256, 0, stream>>>(W_enc, WT);
    gemm_kernel<<<dim3(D_SAE / 128, BATCH / 128), 256, 0, stream>>>(xch, WT, b_enc, pre);
    topk_loss_kernel<<<BATCH, 1024, 0, stream>>>(pre, x, W_dec, b_dec, out);
}

// Round 2
// 362.177 us; speedup vs baseline: 1.3165x; 1.3165x over previous
//
#include <hip/hip_runtime.h>
#include <hip/hip_bf16.h>
#include <stdint.h>
#include <string.h>

#define D_IN 768
#define D_SAE 24576
#define BATCH 2048
#define TOPK 64

typedef _Float16 f16x8 __attribute__((ext_vector_type(8)));
typedef _Float16 f16x4 __attribute__((ext_vector_type(4)));
typedef float floatx4 __attribute__((ext_vector_type(4)));

#define AS1 __attribute__((address_space(1)))
#define AS3 __attribute__((address_space(3)))

// async global->LDS, 16B per lane, wave-uniform LDS base (HW adds lane*16)
__device__ __forceinline__ void load_lds16(const void* g, void* l) {
    __builtin_amdgcn_global_load_lds((AS1 void*)(g), (AS3 void*)(l), 16, 0, 0);
}

// ---------------- prep: xc = x - b_dec (f16), zero the loss accumulator ----
__global__ __launch_bounds__(256) void prep_x_kernel(const float* __restrict__ x,
                                                     const float* __restrict__ b_dec,
                                                     _Float16* __restrict__ xch,
                                                     float* __restrict__ out) {
    if (blockIdx.x == 0 && threadIdx.x == 0) out[0] = 0.0f;
    int i = (blockIdx.x * 256 + threadIdx.x) * 4;
    if (i >= BATCH * D_IN) return;
    int c = i % D_IN;
    float4 xv = *(const float4*)(x + i);
    float4 bv = *(const float4*)(b_dec + c);
    f16x4 h;
    h[0] = (_Float16)(xv.x - bv.x);
    h[1] = (_Float16)(xv.y - bv.y);
    h[2] = (_Float16)(xv.z - bv.z);
    h[3] = (_Float16)(xv.w - bv.w);
    *(f16x4*)(xch + i) = h;
}

// ---------------- transpose W_enc [768, 24576] f32 -> WT [24576, 768] f16 --
__global__ __launch_bounds__(256) void transpose_kernel(const float* __restrict__ W,
                                                        _Float16* __restrict__ WT) {
    __shared__ _Float16 tile[32][33];
    int n0 = blockIdx.x * 32;   // over D_SAE
    int k0 = blockIdx.y * 32;   // over D_IN
    int tx = threadIdx.x & 31, ty = threadIdx.x >> 5;
#pragma unroll
    for (int r = 0; r < 4; ++r) {
        int k = k0 + ty + r * 8;
        tile[ty + r * 8][tx] = (_Float16)W[(size_t)k * D_SAE + n0 + tx];
    }
    __syncthreads();
#pragma unroll
    for (int r = 0; r < 4; ++r) {
        int n = n0 + ty + r * 8;
        WT[(size_t)n * D_IN + k0 + tx] = tile[tx][ty + r * 8];
    }
}

// ---------------- GEMM: pre_keys[2048,24576] = key(f16(xch @ WT^T + b_enc)) -
// A = xch [BATCH, 768] f16 row-major; B^T = WT [D_SAE, 768] f16 row-major.
// 128x128 tile, BK=32, 4 waves (2x2 of 64x64), 16x16x32 f16 MFMA.
// Output: 16-bit monotone keys (unsigned compare == float compare).
__global__ __launch_bounds__(256) void gemm_kernel(const _Float16* __restrict__ A,
                                                   const _Float16* __restrict__ BT,
                                                   const float* __restrict__ b_enc,
                                                   unsigned short* __restrict__ pre) {
    __shared__ _Float16 As[128 * 32];
    __shared__ _Float16 Bs[128 * 32];
    const int tid = threadIdx.x;
    const int lane = tid & 63;
    const int wave = tid >> 6;
    const int m0 = blockIdx.x * 128;   // M is the FAST grid dim (L2 reuse of WT slab)
    const int n0 = blockIdx.y * 128;
    const int wm = wave >> 1, wn = wave & 1;
    const int colv = lane & 15, quad = lane >> 4;

    floatx4 acc[4][4];
#pragma unroll
    for (int mi = 0; mi < 4; ++mi)
#pragma unroll
        for (int ni = 0; ni < 4; ++ni)
#pragma unroll
            for (int r = 0; r < 4; ++r) acc[mi][ni][r] = 0.0f;

    for (int kt = 0; kt < 24; ++kt) {
        const int k0 = kt * 32;
#pragma unroll
        for (int i = 0; i < 2; ++i) {
            int gw = i * 256 + wave * 64;   // wave-uniform base granule
            int g = gw + lane;              // this lane's granule
            int r = g >> 2, kq = g & 3;
            load_lds16(A + (size_t)(m0 + r) * D_IN + k0 + kq * 8, &As[gw * 8]);
            load_lds16(BT + (size_t)(n0 + r) * D_IN + k0 + kq * 8, &Bs[gw * 8]);
        }
        __syncthreads();
        f16x8 af[4], bf[4];
#pragma unroll
        for (int mi = 0; mi < 4; ++mi)
            af[mi] = *(const f16x8*)&As[(wm * 64 + mi * 16 + colv) * 32 + quad * 8];
#pragma unroll
        for (int ni = 0; ni < 4; ++ni)
            bf[ni] = *(const f16x8*)&Bs[(wn * 64 + ni * 16 + colv) * 32 + quad * 8];
#pragma unroll
        for (int mi = 0; mi < 4; ++mi)
#pragma unroll
            for (int ni = 0; ni < 4; ++ni)
                acc[mi][ni] = __builtin_amdgcn_mfma_f32_16x16x32_f16(af[mi], bf[ni], acc[mi][ni], 0, 0, 0);
        __syncthreads();
    }
    // epilogue: C/D layout col=lane&15, row=quad*4+reg
    float be[4];
#pragma unroll
    for (int ni = 0; ni < 4; ++ni) be[ni] = b_enc[n0 + wn * 64 + ni * 16 + colv];
#pragma unroll
    for (int mi = 0; mi < 4; ++mi) {
#pragma unroll
        for (int ni = 0; ni < 4; ++ni) {
            size_t base = (size_t)(m0 + wm * 64 + mi * 16 + quad * 4) * D_SAE
                        + (size_t)(n0 + wn * 64 + ni * 16 + colv);
#pragma unroll
            for (int r = 0; r < 4; ++r) {
                _Float16 h = (_Float16)(acc[mi][ni][r] + be[ni]);
                unsigned short u;
                __builtin_memcpy(&u, &h, 2);
                unsigned short key = u ^ ((u & 0x8000) ? 0xFFFFu : 0x8000u);
                pre[base + (size_t)r * D_SAE] = key;
            }
        }
    }
}

// ---------------- fused exact top-64 on 16-bit keys + sparse decode + loss -
// 384 threads (6 waves); each thread holds 64 keys (32 packed uints).
#define TKT 384
#define KPT 64   // keys per thread = D_SAE / TKT
__global__ __launch_bounds__(TKT) void topk_loss_kernel(const unsigned short* __restrict__ pre,
                                                        const float* __restrict__ x,
                                                        const float* __restrict__ W_dec,
                                                        const float* __restrict__ b_dec,
                                                        float* __restrict__ out) {
    const int row = blockIdx.x;
    const int tid = threadIdx.x;
    const int lane = tid & 63, wv = tid >> 6;

    __shared__ int hist[256];
    __shared__ int wtot[6];
    __shared__ float wred[6];
    __shared__ int sh_cnt, sh_B, sh_K, na, ne;
    __shared__ int sel_idx[TOPK];
    __shared__ float sel_val[TOPK];

    // ---- load this thread's contiguous 64 keys (8 x 16B) ----
    const uint4* kp = (const uint4*)(pre + (size_t)row * D_SAE) + tid * 8;
    unsigned w[32];
#pragma unroll
    for (int i = 0; i < 8; ++i) {
        uint4 v = kp[i];
        w[i * 4 + 0] = v.x; w[i * 4 + 1] = v.y; w[i * 4 + 2] = v.z; w[i * 4 + 3] = v.w;
    }
    const int colbase = tid * KPT;

    // ---- phase 1: count keys >= key(2.0) = 0xC000 (cheap pre-filter) ----
    if (tid == 0) sh_cnt = 0;
    __syncthreads();
    int c = 0;
#pragma unroll
    for (int q = 0; q < 32; ++q) {
        c += ((w[q] & 0xFFFFu) >= 0xC000u);
        c += ((w[q] >> 16) >= 0xC000u);
    }
#pragma unroll
    for (int off = 32; off > 0; off >>= 1) c += __shfl_down(c, off, 64);
    if (lane == 0) atomicAdd(&sh_cnt, c);
    __syncthreads();
    // fast path: histogram only the ~560 values >= 2.0; fallback: all values
    const unsigned lim = (sh_cnt >= TOPK) ? 0xC000u : 0u;

    // ---- radix pass 1: high byte ----
    if (tid < 256) hist[tid] = 0;
    __syncthreads();
#pragma unroll
    for (int q = 0; q < 32; ++q) {
        unsigned k0 = w[q] & 0xFFFFu, k1 = w[q] >> 16;
        if (k0 >= lim) atomicAdd(&hist[k0 >> 8], 1);
        if (k1 >= lim) atomicAdd(&hist[k1 >> 8], 1);
    }
    __syncthreads();
    int K = TOPK;
    {   // suffix-scan + threshold-bin select (bins owned by tid<256)
        int h = 0, s = 0;
        if (tid < 256) { h = hist[tid]; s = h; }
#pragma unroll
        for (int off = 1; off < 64; off <<= 1) {
            int v = __shfl_down(s, off, 64);
            if (lane + off < 64) s += v;
        }
        if (tid < 256 && lane == 0) wtot[wv] = s;
        __syncthreads();
        if (tid < 256) {
            for (int w2 = wv + 1; w2 < 4; ++w2) s += wtot[w2];
            int G = s - h;
            if (G < K && s >= K) { sh_B = tid; sh_K = K - G; }
        }
        __syncthreads();
    }
    const unsigned B = (unsigned)sh_B;
    K = sh_K;
    __syncthreads();

    // ---- radix pass 2: low byte within bin B ----
    if (tid < 256) hist[tid] = 0;
    __syncthreads();
#pragma unroll
    for (int q = 0; q < 32; ++q) {
        unsigned k0 = w[q] & 0xFFFFu, k1 = w[q] >> 16;
        if ((k0 >> 8) == B) atomicAdd(&hist[k0 & 0xFF], 1);
        if ((k1 >> 8) == B) atomicAdd(&hist[k1 & 0xFF], 1);
    }
    __syncthreads();
    {
        int h = 0, s = 0;
        if (tid < 256) { h = hist[tid]; s = h; }
#pragma unroll
        for (int off = 1; off < 64; off <<= 1) {
            int v = __shfl_down(s, off, 64);
            if (lane + off < 64) s += v;
        }
        if (tid < 256 && lane == 0) wtot[wv] = s;
        __syncthreads();
        if (tid < 256) {
            for (int w2 = wv + 1; w2 < 4; ++w2) s += wtot[w2];
            int G = s - h;
            if (G < K && s >= K) { sh_B = tid; sh_K = K - G; }
        }
        __syncthreads();
    }
    const unsigned T = (B << 8) | (unsigned)sh_B;   // key of the 64th largest
    const int K2 = sh_K;                            // #ties at T to take
    const int nGreater = TOPK - K2;

    // ---- final: collect exactly 64 (idx, relu(val)) ----
    if (tid == 0) { na = 0; ne = 0; }
    __syncthreads();
#pragma unroll
    for (int q = 0; q < 32; ++q) {
#pragma unroll
        for (int half = 0; half < 2; ++half) {
            unsigned k = half ? (w[q] >> 16) : (w[q] & 0xFFFFu);
            int col = colbase + q * 2 + half;
            int slot = -1;
            if (k > T) slot = atomicAdd(&na, 1);
            else if (k == T) {
                int e = atomicAdd(&ne, 1);
                if (e < K2) slot = nGreater + e;
            }
            if (slot >= 0) {
                unsigned short u = (unsigned short)((k & 0x8000u) ? (k ^ 0x8000u) : (k ^ 0xFFFFu));
                _Float16 h;
                __builtin_memcpy(&h, &u, 2);
                float v = (float)h;
                sel_idx[slot] = col;
                sel_val[slot] = fmaxf(v, 0.0f);   // relu
            }
        }
    }
    __syncthreads();

    // ---- sparse decode + squared-error: 2 columns per thread ----
    const int c0 = tid, c1 = tid + TKT;   // both < 768
    const float* xr = x + (size_t)row * D_IN;
    float r0 = b_dec[c0], r1 = b_dec[c1];
#pragma unroll 8
    for (int s = 0; s < TOPK; ++s) {
        float v = sel_val[s];
        const float* wr = W_dec + (size_t)sel_idx[s] * D_IN;
        r0 += v * wr[c0];
        r1 += v * wr[c1];
    }
    float d0 = r0 - xr[c0], d1 = r1 - xr[c1];
    float local = d0 * d0 + d1 * d1;

    // ---- block reduce -> one atomic per row ----
#pragma unroll
    for (int off = 32; off > 0; off >>= 1) local += __shfl_down(local, off, 64);
    if (lane == 0) wred[wv] = local;
    __syncthreads();
    if (tid == 0) {
        float s = 0.0f;
#pragma unroll
        for (int i = 0; i < 6; ++i) s += wred[i];
        atomicAdd(out, s);
    }
}

extern "C" void kernel_launch(void* const* d_in, const int* in_sizes, int n_in,
                              void* d_out, int out_size, void* d_ws, size_t ws_size,
                              hipStream_t stream) {
    const float* x     = (const float*)d_in[0];
    const float* W_enc = (const float*)d_in[1];
    const float* W_dec = (const float*)d_in[2];
    const float* b_enc = (const float*)d_in[3];
    const float* b_dec = (const float*)d_in[4];
    float* out = (float*)d_out;

    char* ws = (char*)d_ws;
    _Float16* xch      = (_Float16*)ws;                      // 2048*768*2   = 3,145,728 B
    _Float16* WT       = (_Float16*)(ws + 3145728);          // 24576*768*2  = 37,748,736 B
    unsigned short* pre = (unsigned short*)(ws + 3145728 + 37748736); // 2048*24576*2 = 100,663,296 B

    prep_x_kernel<<<1536, 256, 0, stream>>>(x, b_dec, xch, out);
    transpose_kernel<<<dim3(D_SAE / 32, D_IN / 32), 256, 0, stream>>>(W_enc, WT);
    // M-tile fast in x for L2 reuse of the WT slab across co-resident blocks
    gemm_kernel<<<dim3(BATCH / 128, D_SAE / 128), 256, 0, stream>>>(xch, WT, b_enc, pre);
    topk_loss_kernel<<<BATCH, TKT, 0, stream>>>(pre, x, W_dec, b_dec, out);
}